// Round 1
// baseline (254.245 us; speedup 1.0000x reference)
//
#include <hip/hip_runtime.h>

typedef _Float16 half8 __attribute__((ext_vector_type(8)));
typedef float floatx4 __attribute__((ext_vector_type(4)));

static constexpr float INV2PI = 0.15915494309189535f;  // fold FREQ & rad->rev into weights
static constexpr float RLOG   = 3.82843f;

// Pre-activation arrives already scaled to revolutions (weights pre-scaled by 1/2pi).
__device__ __forceinline__ float act_rev(float a) {
    float c = __builtin_amdgcn_cosf(a);        // v_cos_f32, input in revolutions, |a| <= ~1.4 rev
    float x = __builtin_fmaf(c, 0.5f, 0.5f);
    float t = RLOG * x;                         // logistic iter 1: x = R*x*(1-x) = t - t*x
    x = __builtin_fmaf(-t, x, t);
    t = RLOG * x;                               // logistic iter 2
    x = __builtin_fmaf(-t, x, t);
    return x;
}

// One wave owns 16 rows end-to-end. No inter-wave communication, no barriers.
// LDS H buffer per wave: 16 rows x 72 halfs (64 + 8 pad -> 2-way (free) bank access
// for both the A-frag ds_read_b128 and the epilogue b16 scatter).
__global__ __launch_bounds__(256) void mlp_fused(
    const float* __restrict__ x,
    const float* __restrict__ W1, const float* __restrict__ b1,
    const float* __restrict__ W2, const float* __restrict__ b2,
    const float* __restrict__ W3, const float* __restrict__ b3,
    const float* __restrict__ W4, const float* __restrict__ b4,
    float* __restrict__ out, int N)
{
    __shared__ alignas(16) _Float16 Hs[4][16 * 72];
    const int lane = threadIdx.x & 63;
    const int wib  = threadIdx.x >> 6;
    const int m    = lane & 15;   // A-frag row / C-frag col
    const int q    = lane >> 4;   // quad
    _Float16* H = Hs[wib];

    // ---------------- per-wave weight prep (registers, reused across 8 tiles) ------------
    // B-frag layout (16x16x32 f16): B[n = lane&15 + 16t][k = 32s + q*8 + j]
    half8 bf1[4];      floatx4 bb1;
    half8 bf2[4][2];   floatx4 bb2;
    half8 bf3[4][2];   floatx4 bb3;
    half8 bf4[2];      float   b4s;

    #pragma unroll
    for (int t = 0; t < 4; ++t) {
        const int n = m + 16 * t;
        // Layer 1: K=2 padded into k-slots 0..5 with hi/lo split of W1 (and of x below):
        // A slots: [xh, xl, yh, yl, xh, yh, 0, 0]
        // B slots: [w0h,w0h,w1h,w1h,w0l,w1l, 0, 0]
        half8 v = {};
        if (q == 0) {
            float w0 = W1[2*n]   * INV2PI;
            float w1 = W1[2*n+1] * INV2PI;
            _Float16 w0h = (_Float16)w0; float w0l = w0 - (float)w0h;
            _Float16 w1h = (_Float16)w1; float w1l = w1 - (float)w1h;
            v[0] = w0h; v[1] = w0h; v[2] = w1h; v[3] = w1h;
            v[4] = (_Float16)w0l; v[5] = (_Float16)w1l;
        }
        bf1[t] = v;
        bb1[t] = b1[n] * INV2PI;
        bb2[t] = b2[n] * INV2PI;
        bb3[t] = b3[n] * INV2PI;
        #pragma unroll
        for (int s = 0; s < 2; ++s) {
            const float* p2 = W2 + n * 64 + s * 32 + q * 8;
            const float* p3 = W3 + n * 64 + s * 32 + q * 8;
            half8 v2, v3;
            #pragma unroll
            for (int j = 0; j < 8; ++j) {
                v2[j] = (_Float16)(p2[j] * INV2PI);
                v3[j] = (_Float16)(p3[j] * INV2PI);
            }
            bf2[t][s] = v2;
            bf3[t][s] = v3;
        }
    }
    #pragma unroll
    for (int s = 0; s < 2; ++s) {           // layer 4: only output col n==0 is real
        half8 v = {};
        if (m == 0) {
            const float* p4 = W4 + s * 32 + q * 8;
            #pragma unroll
            for (int j = 0; j < 8; ++j) v[j] = (_Float16)(p4[j] * INV2PI);
        }
        bf4[s] = v;
    }
    b4s = b4[0] * INV2PI;

    const int ntiles = N >> 4;
    const int nwaves = (gridDim.x * blockDim.x) >> 6;
    const int gwave  = (int)(blockIdx.x * blockDim.x + threadIdx.x) >> 6;
    const float2* __restrict__ x2 = (const float2*)x;

    for (int tile = gwave; tile < ntiles; tile += nwaves) {
        const int m0 = tile << 4;

        // ---- layer 1: x[16,2] -> h1[16,64], hi/lo f16 split for fp32-grade precision ----
        float2 xv = x2[m0 + m];               // quads duplicate the same 128B segment
        _Float16 xh = (_Float16)xv.x; float xl = xv.x - (float)xh;
        _Float16 yh = (_Float16)xv.y; float yl = xv.y - (float)yh;
        half8 a1 = {};
        if (q == 0) {
            a1[0] = xh; a1[1] = (_Float16)xl;
            a1[2] = yh; a1[3] = (_Float16)yl;
            a1[4] = xh; a1[5] = yh;
        }
        #pragma unroll
        for (int t = 0; t < 4; ++t) {
            floatx4 acc;
            #pragma unroll
            for (int r = 0; r < 4; ++r) acc[r] = bb1[t];
            acc = __builtin_amdgcn_mfma_f32_16x16x32_f16(a1, bf1[t], acc, 0, 0, 0);
            // C layout: row = q*4+r, col = m+16t  -> activate, cast f16, scatter to LDS
            #pragma unroll
            for (int r = 0; r < 4; ++r)
                H[(q * 4 + r) * 72 + m + 16 * t] = (_Float16)act_rev(acc[r]);
        }

        // ---- layer 2: h1 @ W2^T ----
        half8 ha0 = *(const half8*)&H[m * 72 + q * 8];        // A[m][k], k in [0,32)
        half8 ha1 = *(const half8*)&H[m * 72 + 32 + q * 8];   // k in [32,64)
        #pragma unroll
        for (int t = 0; t < 4; ++t) {
            floatx4 acc;
            #pragma unroll
            for (int r = 0; r < 4; ++r) acc[r] = bb2[t];
            acc = __builtin_amdgcn_mfma_f32_16x16x32_f16(ha0, bf2[t][0], acc, 0, 0, 0);
            acc = __builtin_amdgcn_mfma_f32_16x16x32_f16(ha1, bf2[t][1], acc, 0, 0, 0);
            #pragma unroll
            for (int r = 0; r < 4; ++r)
                H[(q * 4 + r) * 72 + m + 16 * t] = (_Float16)act_rev(acc[r]);
        }

        // ---- layer 3: h2 @ W3^T ----
        half8 hb0 = *(const half8*)&H[m * 72 + q * 8];
        half8 hb1 = *(const half8*)&H[m * 72 + 32 + q * 8];
        #pragma unroll
        for (int t = 0; t < 4; ++t) {
            floatx4 acc;
            #pragma unroll
            for (int r = 0; r < 4; ++r) acc[r] = bb3[t];
            acc = __builtin_amdgcn_mfma_f32_16x16x32_f16(hb0, bf3[t][0], acc, 0, 0, 0);
            acc = __builtin_amdgcn_mfma_f32_16x16x32_f16(hb1, bf3[t][1], acc, 0, 0, 0);
            #pragma unroll
            for (int r = 0; r < 4; ++r)
                H[(q * 4 + r) * 72 + m + 16 * t] = (_Float16)act_rev(acc[r]);
        }

        // ---- layer 4: h3 @ W4^T (only col 0 real) + final activation + store ----
        half8 hc0 = *(const half8*)&H[m * 72 + q * 8];
        half8 hc1 = *(const half8*)&H[m * 72 + 32 + q * 8];
        floatx4 acc4;
        {
            float binit = (m == 0) ? b4s : 0.0f;
            #pragma unroll
            for (int r = 0; r < 4; ++r) acc4[r] = binit;
        }
        acc4 = __builtin_amdgcn_mfma_f32_16x16x32_f16(hc0, bf4[0], acc4, 0, 0, 0);
        acc4 = __builtin_amdgcn_mfma_f32_16x16x32_f16(hc1, bf4[1], acc4, 0, 0, 0);
        if (m == 0) {
            floatx4 o;
            #pragma unroll
            for (int r = 0; r < 4; ++r) o[r] = act_rev(acc4[r]);
            // rows q*4 .. q*4+3 -> contiguous, 16B-aligned float4 store
            *(floatx4*)(out + m0 + q * 4) = o;
        }
    }
}

extern "C" void kernel_launch(void* const* d_in, const int* in_sizes, int n_in,
                              void* d_out, int out_size, void* d_ws, size_t ws_size,
                              hipStream_t stream) {
    const float* x  = (const float*)d_in[0];
    const float* W1 = (const float*)d_in[1];
    const float* b1 = (const float*)d_in[2];
    const float* W2 = (const float*)d_in[3];
    const float* b2 = (const float*)d_in[4];
    const float* W3 = (const float*)d_in[5];
    const float* b3 = (const float*)d_in[6];
    const float* W4 = (const float*)d_in[7];
    const float* b4 = (const float*)d_in[8];
    float* out = (float*)d_out;
    const int N = out_size;          // 2097152, divisible by 16

    // 4096 blocks x 4 waves = 16384 waves; 131072 tiles of 16 rows -> 8 tiles/wave,
    // weight-prep amortized 8x, plenty of blocks for occupancy-round balance.
    mlp_fused<<<dim3(4096), dim3(256), 0, stream>>>(x, W1, b1, W2, b2, W3, b3, W4, b4, out, N);
}

// Round 2
// 233.346 us; speedup vs baseline: 1.0896x; 1.0896x over previous
//
#include <hip/hip_runtime.h>

typedef _Float16 half4v __attribute__((ext_vector_type(4)));
typedef float floatx4 __attribute__((ext_vector_type(4)));

static constexpr float INV2PI = 0.15915494309189535f;  // fold rad->rev into weights
static constexpr float RLOG   = 3.82843f;

// Pre-activation arrives already scaled to revolutions (weights pre-scaled by 1/2pi).
__device__ __forceinline__ float act_rev(float a) {
    float c = __builtin_amdgcn_cosf(a);        // v_cos_f32, input in revolutions
    float x = __builtin_fmaf(c, 0.5f, 0.5f);
    float t = RLOG * x;                         // logistic iter 1
    x = __builtin_fmaf(-t, x, t);
    t = RLOG * x;                               // logistic iter 2
    x = __builtin_fmaf(-t, x, t);
    return x;
}

// Transpose-free register-resident MLP chain:
// state invariant: S[c] holds G[in_neuron = 16c + 4q + j][sample = lane&15] as f16,
// which IS the B-frag layout of v_mfma_f32_16x16x16f16. Each layer computes
// C = W_block * G (A = weight frag, B = state); C-layout (col=lane&15,row=4q+r)
// equals the B-frag layout, so act+cast re-establishes the invariant. No LDS.
__global__ __launch_bounds__(256) void mlp_fused(
    const float* __restrict__ x,
    const float* __restrict__ W1, const float* __restrict__ b1,
    const float* __restrict__ W2, const float* __restrict__ b2,
    const float* __restrict__ W3, const float* __restrict__ b3,
    const float* __restrict__ W4, const float* __restrict__ b4,
    float* __restrict__ out, int N)
{
    const int lane = threadIdx.x & 63;
    const int m    = lane & 15;   // sample slot / A-frag row
    const int q    = lane >> 4;   // quad -> k-subchunk

    const floatx4 zero4 = {0.0f, 0.0f, 0.0f, 0.0f};

    // ---------------- per-wave weight prep (registers, reused across 8 tiles) ----------
    half4v w1f[4];        // layer1 A-frags: W1 hi/lo + b1 hi/lo packed into K slots
    half4v w2f[4][4];     // [t_out][k_chunk]
    half4v w3f[4][4];
    half4v w4f[4];        // [k_chunk], only m==0 rows nonzero
    half4v b2f[4], b3f[4];// bias-chunk A-frags: q==0 -> [b_hi, b_lo, 0, 0]
    half4v ones = {};     // bias-chunk B-frag: q==0 -> [1, 1, 0, 0]
    if (q == 0) { ones[0] = (_Float16)1.0f; ones[1] = (_Float16)1.0f; }

    #pragma unroll
    for (int t = 0; t < 4; ++t) {
        const int n = 16 * t + m;              // out-neuron for this lane
        // Layer 1 frag. K-slot pairing (A slot k vs B slot k):
        //   q0: [w0h, w0h, w1h, w1h]  <->  [xh, xl, yh, yl]
        //   q1: [w0l, w1l, b1h, b1l]  <->  [xh, yh, 1,  1 ]
        half4v v = {};
        if (q == 0) {
            float w0 = W1[2*n]   * INV2PI;
            float w1 = W1[2*n+1] * INV2PI;
            _Float16 w0h = (_Float16)w0;
            _Float16 w1h = (_Float16)w1;
            v[0] = w0h; v[1] = w0h; v[2] = w1h; v[3] = w1h;
        } else if (q == 1) {
            float w0 = W1[2*n]   * INV2PI;
            float w1 = W1[2*n+1] * INV2PI;
            _Float16 w0h = (_Float16)w0; float w0l = w0 - (float)w0h;
            _Float16 w1h = (_Float16)w1; float w1l = w1 - (float)w1h;
            float bb = b1[n] * INV2PI;
            _Float16 bh = (_Float16)bb; float bl = bb - (float)bh;
            v[0] = (_Float16)w0l; v[1] = (_Float16)w1l;
            v[2] = bh;            v[3] = (_Float16)bl;
        }
        w1f[t] = v;

        half4v vb2 = {}, vb3 = {};
        if (q == 0) {
            float bb = b2[n] * INV2PI;
            _Float16 bh = (_Float16)bb; float bl = bb - (float)bh;
            vb2[0] = bh; vb2[1] = (_Float16)bl;
            bb = b3[n] * INV2PI;
            bh = (_Float16)bb; bl = bb - (float)bh;
            vb3[0] = bh; vb3[1] = (_Float16)bl;
        }
        b2f[t] = vb2;
        b3f[t] = vb3;

        #pragma unroll
        for (int c = 0; c < 4; ++c) {
            const float* p2 = W2 + n * 64 + 16 * c + 4 * q;
            const float* p3 = W3 + n * 64 + 16 * c + 4 * q;
            half4v v2, v3;
            #pragma unroll
            for (int j = 0; j < 4; ++j) {
                v2[j] = (_Float16)(p2[j] * INV2PI);
                v3[j] = (_Float16)(p3[j] * INV2PI);
            }
            w2f[t][c] = v2;
            w3f[t][c] = v3;
        }
    }
    #pragma unroll
    for (int c = 0; c < 4; ++c) {             // layer 4: only output row m==0 is real
        half4v v = {};
        if (m == 0) {
            const float* p4 = W4 + 16 * c + 4 * q;
            #pragma unroll
            for (int j = 0; j < 4; ++j) v[j] = (_Float16)(p4[j] * INV2PI);
        }
        w4f[c] = v;
    }
    const float b4s = b4[0] * INV2PI;

    const int ntiles = N >> 4;
    const int nwaves = (gridDim.x * blockDim.x) >> 6;
    const int gwave  = (int)(blockIdx.x * blockDim.x + threadIdx.x) >> 6;
    const float2* __restrict__ x2 = (const float2*)x;

    for (int tile = gwave; tile < ntiles; tile += nwaves) {
        const int m0 = tile << 4;

        // ---- layer 1: B-frag from x (hi/lo split), bias rides in k-slots 6,7 ----
        float2 xv = x2[m0 + m];               // quads duplicate the same 128B segment
        half4v xa = {};
        if (q == 0) {
            _Float16 xh = (_Float16)xv.x; float xl = xv.x - (float)xh;
            _Float16 yh = (_Float16)xv.y; float yl = xv.y - (float)yh;
            xa[0] = xh; xa[1] = (_Float16)xl;
            xa[2] = yh; xa[3] = (_Float16)yl;
        } else if (q == 1) {
            xa[0] = (_Float16)xv.x; xa[1] = (_Float16)xv.y;
            xa[2] = (_Float16)1.0f; xa[3] = (_Float16)1.0f;
        }

        half4v S[4], NS[4];
        #pragma unroll
        for (int t = 0; t < 4; ++t) {
            floatx4 acc = __builtin_amdgcn_mfma_f32_16x16x16f16(w1f[t], xa, zero4, 0, 0, 0);
            #pragma unroll
            for (int r = 0; r < 4; ++r) S[t][r] = (_Float16)act_rev(acc[r]);
        }

        // ---- layer 2: bias chunk + 4 K-chunks ----
        #pragma unroll
        for (int t = 0; t < 4; ++t) {
            floatx4 acc = __builtin_amdgcn_mfma_f32_16x16x16f16(b2f[t], ones, zero4, 0, 0, 0);
            #pragma unroll
            for (int c = 0; c < 4; ++c)
                acc = __builtin_amdgcn_mfma_f32_16x16x16f16(w2f[t][c], S[c], acc, 0, 0, 0);
            #pragma unroll
            for (int r = 0; r < 4; ++r) NS[t][r] = (_Float16)act_rev(acc[r]);
        }

        // ---- layer 3 ----
        #pragma unroll
        for (int t = 0; t < 4; ++t) {
            floatx4 acc = __builtin_amdgcn_mfma_f32_16x16x16f16(b3f[t], ones, zero4, 0, 0, 0);
            #pragma unroll
            for (int c = 0; c < 4; ++c)
                acc = __builtin_amdgcn_mfma_f32_16x16x16f16(w3f[t][c], NS[c], acc, 0, 0, 0);
            #pragma unroll
            for (int r = 0; r < 4; ++r) S[t][r] = (_Float16)act_rev(acc[r]);
        }

        // ---- layer 4: row 0 only; bias uniform -> acc init ----
        floatx4 a4 = {b4s, b4s, b4s, b4s};
        #pragma unroll
        for (int c = 0; c < 4; ++c)
            a4 = __builtin_amdgcn_mfma_f32_16x16x16f16(w4f[c], S[c], a4, 0, 0, 0);

        if (q == 0)                            // lanes 0..15 hold C[0][sample] in reg 0
            out[m0 + m] = act_rev(a4[0]);      // 16 lanes x 4B contiguous = 64B store
    }
}

extern "C" void kernel_launch(void* const* d_in, const int* in_sizes, int n_in,
                              void* d_out, int out_size, void* d_ws, size_t ws_size,
                              hipStream_t stream) {
    const float* x  = (const float*)d_in[0];
    const float* W1 = (const float*)d_in[1];
    const float* b1 = (const float*)d_in[2];
    const float* W2 = (const float*)d_in[3];
    const float* b2 = (const float*)d_in[4];
    const float* W3 = (const float*)d_in[5];
    const float* b3 = (const float*)d_in[6];
    const float* W4 = (const float*)d_in[7];
    const float* b4 = (const float*)d_in[8];
    float* out = (float*)d_out;
    const int N = out_size;          // 2097152, divisible by 16

    // 4096 blocks x 4 waves = 16384 waves; 131072 tiles -> exactly 8 tiles/wave.
    mlp_fused<<<dim3(4096), dim3(256), 0, stream>>>(x, W1, b1, W2, b2, W3, b3, W4, b4, out, N);
}

// Round 4
// 224.753 us; speedup vs baseline: 1.1312x; 1.0382x over previous
//
#include <hip/hip_runtime.h>

typedef _Float16 half8  __attribute__((ext_vector_type(8)));
typedef _Float16 half4v __attribute__((ext_vector_type(4)));
typedef _Float16 half2v __attribute__((ext_vector_type(2)));
typedef __fp16   fp16x2 __attribute__((ext_vector_type(2)));
typedef float    floatx4 __attribute__((ext_vector_type(4)));
typedef float    float2v __attribute__((ext_vector_type(2)));

static constexpr float INV2PI = 0.15915494309189535f;  // fold rad->rev into weights
static constexpr float RLOG   = 3.82843f;

// act(a) with a in revolutions: x0 = 0.5+0.5cos -> two logistic iters.
// Algebra: x0(1-x0) = 0.25 - 0.25 c^2 = p;  out = R^2 * p * (1 - R*p).
__device__ __forceinline__ float act_rev(float a) {
    float c = __builtin_amdgcn_cosf(a);
    float qq = c * c;
    float p = __builtin_fmaf(qq, -0.25f, 0.25f);
    float w = __builtin_fmaf(p, -RLOG, 1.0f);
    return (RLOG * RLOG * p) * w;
}

// Vectorized over 4 accumulator values -> 4 packed f16 (cvt_pkrtz).
__device__ __forceinline__ half4v act4(floatx4 a) {
    float2v c0 = { __builtin_amdgcn_cosf(a[0]), __builtin_amdgcn_cosf(a[1]) };
    float2v c1 = { __builtin_amdgcn_cosf(a[2]), __builtin_amdgcn_cosf(a[3]) };
    float2v q0 = c0 * c0, q1 = c1 * c1;
    float2v p0 = __builtin_elementwise_fma(q0, (float2v)(-0.25f), (float2v)(0.25f));
    float2v p1 = __builtin_elementwise_fma(q1, (float2v)(-0.25f), (float2v)(0.25f));
    float2v w0 = __builtin_elementwise_fma(p0, (float2v)(-RLOG), (float2v)(1.0f));
    float2v w1 = __builtin_elementwise_fma(p1, (float2v)(-RLOG), (float2v)(1.0f));
    float2v u0 = p0 * (RLOG * RLOG), u1 = p1 * (RLOG * RLOG);
    float2v h0 = u0 * w0, h1 = u1 * w1;
    half2v lo = __builtin_bit_cast(half2v, __builtin_amdgcn_cvt_pkrtz(h0.x, h0.y));
    half2v hi = __builtin_bit_cast(half2v, __builtin_amdgcn_cvt_pkrtz(h1.x, h1.y));
    return __builtin_shufflevector(lo, hi, 0, 1, 2, 3);
}

__device__ __forceinline__ half8 cat(half4v a, half4v b) {
    return __builtin_shufflevector(a, b, 0, 1, 2, 3, 4, 5, 6, 7);
}

// Register-resident MLP chain on native 16x16x32 f16 MFMA.
// State after each hidden layer: S[t] = 4 f16, lane(m,q) holds C rows 4q..4q+3
// of tile t, col m (= sample). Next layer's weight COLUMNS are permuted by
//   sigma: k-slot (c, q, j) -> neuron  (j<4 ? 16c+4q+j : 16(c+2)+4q+j-4)
// so the B-frag for k-chunk c is exactly cat(S[c], S[c+2]): the layer->layer
// layout transition costs ZERO instructions. Biases enter as f32 C operands.
__global__ __launch_bounds__(256, 3) void mlp_fused(
    const float* __restrict__ x,
    const float* __restrict__ W1, const float* __restrict__ b1,
    const float* __restrict__ W2, const float* __restrict__ b2,
    const float* __restrict__ W3, const float* __restrict__ b3,
    const float* __restrict__ W4, const float* __restrict__ b4,
    float* __restrict__ out, int N)
{
    const int lane = threadIdx.x & 63;
    const int m    = lane & 15;   // sample / C col / A row
    const int q    = lane >> 4;   // quad
    const float s  = INV2PI;
    const floatx4 zero4 = {0.0f, 0.0f, 0.0f, 0.0f};

    // ---------------- per-wave weight prep (reused across 8 tiles) ----------------
    // L1 A-frag (tile t): lanes q==0 hold, for out-neuron n=16t+m, k-slots
    //   [w0h, w0h, w0l, w1h, w1h, w1l, b1h, b1l]   (pairs with xa below)
    half8 w1f[4];
    #pragma unroll
    for (int t = 0; t < 4; ++t) {
        half8 v = {};
        if (q == 0) {
            const int n = 16 * t + m;
            float w0 = W1[2*n] * s, w1 = W1[2*n+1] * s, bb = b1[n] * s;
            _Float16 w0h = (_Float16)w0; float w0l = w0 - (float)w0h;
            _Float16 w1h = (_Float16)w1; float w1l = w1 - (float)w1h;
            _Float16 bh  = (_Float16)bb; float bl  = bb - (float)bh;
            v[0] = w0h; v[1] = w0h; v[2] = (_Float16)w0l;
            v[3] = w1h; v[4] = w1h; v[5] = (_Float16)w1l;
            v[6] = bh;  v[7] = (_Float16)bl;
        }
        w1f[t] = v;
    }

    // L2/L3 A-frags with sigma-permuted columns: two contiguous float4 loads.
    half8 w2f[4][2], w3f[4][2];
    floatx4 bb2[4], bb3[4];
    #pragma unroll
    for (int t = 0; t < 4; ++t) {
        const float* r2 = W2 + (16 * t + m) * 64;
        const float* r3 = W3 + (16 * t + m) * 64;
        #pragma unroll
        for (int c = 0; c < 2; ++c) {
            floatx4 lo2 = *(const floatx4*)(r2 + 16 * c + 4 * q);
            floatx4 hi2 = *(const floatx4*)(r2 + 16 * (c + 2) + 4 * q);
            floatx4 lo3 = *(const floatx4*)(r3 + 16 * c + 4 * q);
            floatx4 hi3 = *(const floatx4*)(r3 + 16 * (c + 2) + 4 * q);
            half8 v2, v3;
            #pragma unroll
            for (int j = 0; j < 4; ++j) {
                v2[j]     = (_Float16)(lo2[j] * s);
                v2[4 + j] = (_Float16)(hi2[j] * s);
                v3[j]     = (_Float16)(lo3[j] * s);
                v3[4 + j] = (_Float16)(hi3[j] * s);
            }
            w2f[t][c] = v2;
            w3f[t][c] = v3;
        }
        bb2[t] = *(const floatx4*)(b2 + 16 * t + 4 * q) * s;   // C-init: b2[16t+4q+r], exact f32
        bb3[t] = *(const floatx4*)(b3 + 16 * t + 4 * q) * s;
    }

    // L4 A-frag: only out-row m==0 real, same sigma column permutation.
    half8 w4f[2] = {half8{}, half8{}};
    if (m == 0) {
        #pragma unroll
        for (int c = 0; c < 2; ++c) {
            #pragma unroll
            for (int j = 0; j < 8; ++j) {
                int nu = (j < 4) ? (16 * c + 4 * q + j) : (16 * (c + 2) + 4 * q + j - 4);
                w4f[c][j] = (_Float16)(W4[nu] * s);
            }
        }
    }
    floatx4 a4init = zero4;
    if (q == 0) a4init[0] = b4[0] * s;       // C row 0 = (q=0, r=0)

    const int ntiles = N >> 4;
    const int nwaves = (gridDim.x * blockDim.x) >> 6;
    const int gwave  = (int)(blockIdx.x * blockDim.x + threadIdx.x) >> 6;
    const float2* __restrict__ x2 = (const float2*)x;

    int tile = gwave;
    float2 xv = x2[(tile << 4) + m];          // software-pipelined x load
    while (tile < ntiles) {
        const int nt = tile + nwaves;
        float2 xnext;
        if (nt < ntiles) xnext = x2[(nt << 4) + m];

        // L1 B-frag (lanes q==0): [xh, xl, xh, yh, yl, yh, 1, 1]
        half8 xa = {};
        if (q == 0) {
            _Float16 xh = (_Float16)xv.x; float xl = xv.x - (float)xh;
            _Float16 yh = (_Float16)xv.y; float yl = xv.y - (float)yh;
            xa[0] = xh; xa[1] = (_Float16)xl; xa[2] = xh;
            xa[3] = yh; xa[4] = (_Float16)yl; xa[5] = yh;
            xa[6] = (_Float16)1.0f; xa[7] = (_Float16)1.0f;
        }

        // ---- layer 1 ----
        half4v S[4];
        #pragma unroll
        for (int t = 0; t < 4; ++t) {
            floatx4 acc = __builtin_amdgcn_mfma_f32_16x16x32_f16(w1f[t], xa, zero4, 0, 0, 0);
            S[t] = act4(acc);
        }

        // ---- layer 2 (B chunks are free register concats) ----
        half8 B0 = cat(S[0], S[2]), B1 = cat(S[1], S[3]);
        half4v T[4];
        #pragma unroll
        for (int t = 0; t < 4; ++t) {
            floatx4 acc = __builtin_amdgcn_mfma_f32_16x16x32_f16(w2f[t][0], B0, bb2[t], 0, 0, 0);
            acc = __builtin_amdgcn_mfma_f32_16x16x32_f16(w2f[t][1], B1, acc, 0, 0, 0);
            T[t] = act4(acc);
        }

        // ---- layer 3 ----
        half8 C0 = cat(T[0], T[2]), C1 = cat(T[1], T[3]);
        #pragma unroll
        for (int t = 0; t < 4; ++t) {
            floatx4 acc = __builtin_amdgcn_mfma_f32_16x16x32_f16(w3f[t][0], C0, bb3[t], 0, 0, 0);
            acc = __builtin_amdgcn_mfma_f32_16x16x32_f16(w3f[t][1], C1, acc, 0, 0, 0);
            S[t] = act4(acc);
        }

        // ---- layer 4 + store ----
        half8 D0 = cat(S[0], S[2]), D1 = cat(S[1], S[3]);
        floatx4 a4 = __builtin_amdgcn_mfma_f32_16x16x32_f16(w4f[0], D0, a4init, 0, 0, 0);
        a4 = __builtin_amdgcn_mfma_f32_16x16x32_f16(w4f[1], D1, a4, 0, 0, 0);
        if (q == 0)
            out[(tile << 4) + m] = act_rev(a4[0]);

        xv = xnext;
        tile = nt;
    }
}

extern "C" void kernel_launch(void* const* d_in, const int* in_sizes, int n_in,
                              void* d_out, int out_size, void* d_ws, size_t ws_size,
                              hipStream_t stream) {
    const float* x  = (const float*)d_in[0];
    const float* W1 = (const float*)d_in[1];
    const float* b1 = (const float*)d_in[2];
    const float* W2 = (const float*)d_in[3];
    const float* b2 = (const float*)d_in[4];
    const float* W3 = (const float*)d_in[5];
    const float* b3 = (const float*)d_in[6];
    const float* W4 = (const float*)d_in[7];
    const float* b4 = (const float*)d_in[8];
    float* out = (float*)d_out;
    const int N = out_size;          // 2097152, divisible by 16

    // 4096 blocks x 4 waves = 16384 waves; 131072 tiles -> exactly 8 tiles/wave.
    mlp_fused<<<dim3(4096), dim3(256), 0, stream>>>(x, W1, b1, W2, b2, W3, b3, W4, b4, out, N);
}